// Round 9
// baseline (611.535 us; speedup 1.0000x reference)
//
#include <hip/hip_runtime.h>
#include <cstdint>
#include <cstddef>

#define T_STEPS 50
#define B_SZ    1024
#define N_INP   784
#define H_SZ    256
#define L_SZ    10
#define M_TOT   (T_STEPS * B_SZ)   // 51200
#define NK0     26                 // K padded to 26*32 = 832
#define NSLICE  5                  // 5 balanced base-256 digits of rint(Wi*2^40): exact (|Wi|<0.5)
#define BNT_BYTES (NK0 * NSLICE * 1024)   // 133,120 B = one nt's B slices

typedef int v4i  __attribute__((ext_vector_type(4)));
typedef int v16i __attribute__((ext_vector_type(16)));

// ---------------------------------------------------------------------------
// Phase 0a: transpose Wr[h][k] (256x256, fp32) -> WrTz[k][h] (row 256 zeroed
// host-side memsetAsync; dummy gather index hits it).  [R7-verified]
// ---------------------------------------------------------------------------
__global__ __launch_bounds__(256) void transpose_wr(const float* __restrict__ Wr,
                                                    float* __restrict__ WrTz) {
    __shared__ float tile[32][33];
    int bx = blockIdx.x * 32, by = blockIdx.y * 32;
    int tx = threadIdx.x % 32, ty = threadIdx.x / 32;   // 32 x 8
    #pragma unroll
    for (int j = 0; j < 32; j += 8)
        tile[ty + j][tx] = Wr[(size_t)(by + ty + j) * H_SZ + bx + tx];
    __syncthreads();
    #pragma unroll
    for (int j = 0; j < 32; j += 8)
        WrTz[(size_t)(bx + ty + j) * H_SZ + by + tx] = tile[tx][ty + j];
}

// ---------------------------------------------------------------------------
// Phase 0b: Wi -> 5 balanced int8 digits of rint(Wi*2^40), fragment-linear:
// SBp[((nt*26+k0)*5+j)*1024 + lane*16 + byte]; h = nt*32+(lane&31),
// k = k0*32+(lane>>5)*16+byte.  [R5-R8-verified exact, absmax 0]
// ---------------------------------------------------------------------------
__global__ __launch_bounds__(128) void prep_packed(const float* __restrict__ Wi,
                                                   uint8_t* __restrict__ SBp) {
    const int nt   = blockIdx.x;
    const int k0   = blockIdx.y * 2 + (threadIdx.x >> 6);
    const int lane = threadIdx.x & 63;
    const int h    = nt * 32 + (lane & 31);
    const int g    = k0 * 2 + (lane >> 5);     // 16-float group index

    int wd[NSLICE][4] = {};
    #pragma unroll
    for (int u = 0; u < 16; ++u) {
        double wv = 0.0;
        if (g < 49) wv = (double)Wi[(size_t)h * N_INP + g * 16 + u];
        double r = rint(wv * 0x1p40);
        #pragma unroll
        for (int j = 0; j < NSLICE - 1; ++j) {
            double q  = floor((r + 128.0) * 0.00390625);
            double dj = r - 256.0 * q;                     // in [-128,127]
            wd[j][u >> 2] |= ((int)dj & 0xFF) << ((u & 3) * 8);
            r = q;
        }
        wd[NSLICE - 1][u >> 2] |= ((int)r & 0xFF) << ((u & 3) * 8);
    }
    uint8_t* base = SBp + ((size_t)(nt * NK0 + k0) * NSLICE) * 1024 + lane * 16;
    #pragma unroll
    for (int j = 0; j < NSLICE; ++j)
        *(v4i*)(base + (size_t)j * 1024) = (v4i){wd[j][0], wd[j][1], wd[j][2], wd[j][3]};
}

// ---------------------------------------------------------------------------
// Phase 0c: pack X (binary fp32) -> fragment-linear int8 (R6-R8-verified).
// Ap[(mt*26+k0)*1024 + lane*16 + byte]
// ---------------------------------------------------------------------------
__global__ __launch_bounds__(256) void pack_x(const float* __restrict__ X,
                                              uint8_t* __restrict__ Ap) {
    const int mt  = blockIdx.x;       // 1600
    const int tid = threadIdx.x;
    #pragma unroll
    for (int i = 0; i < 7; ++i) {
        int s = tid + i * 256;
        if (s < NK0 * 64) {
            int k0 = s >> 6, lane = s & 63;
            int m = mt * 32 + (lane & 31);
            int g = k0 * 2 + (lane >> 5);
            unsigned int bw[4] = {0u, 0u, 0u, 0u};
            if (g < 49) {
                const float* src = X + (size_t)m * N_INP + g * 16;
                #pragma unroll
                for (int q = 0; q < 4; ++q) {
                    float4 f = *(const float4*)(src + q * 4);
                    bw[q] = (f.x != 0.f ? 1u : 0u) | (f.y != 0.f ? 0x100u : 0u)
                          | (f.z != 0.f ? 0x10000u : 0u) | (f.w != 0.f ? 0x1000000u : 0u);
                }
            }
            *(v4i*)(Ap + ((size_t)(mt * NK0 + k0)) * 1024 + lane * 16) =
                (v4i){(int)bw[0], (int)bw[1], (int)bw[2], (int)bw[3]};
        }
    }
}

// ---------------------------------------------------------------------------
// Phase 1: cur = X @ Wi.T exactly via 5 int8-digit MFMAs.
// Block = 256 thr = 4 waves. The ENTIRE B for this block's nt (130 KB, all
// 26 k0 x 5 slices) is staged into dynamic LDS ONCE; after the single
// barrier the inner loop is barrier-free. Each wave sequentially computes
// 4 m-tiles: per k0 one coalesced A-fragment load (L3-hot Ap) + 5
// ds_read_b128 + 5 MFMAs. acc = 80 AGPRs, ~110 VGPR total -> no spill
// (R8's 228-VGPR/9% occupancy failure mode removed). Grid (100, 8 nt).
// ---------------------------------------------------------------------------
__global__ __launch_bounds__(256) void gemm_i8L(const uint8_t* __restrict__ Ap,
                                                const uint8_t* __restrict__ SBp,
                                                double* __restrict__ cur) {
    extern __shared__ __align__(16) uint8_t Bs[];     // BNT_BYTES = 133,120

    const int tid   = threadIdx.x;
    const int wave  = tid >> 6;
    const int lane  = tid & 63;
    const int ghalf = lane >> 5;
    const int nt    = blockIdx.y;

    // --- stage this nt's full B (contiguous chunk) into LDS, once ---
    {
        const uint8_t* src = SBp + (size_t)nt * BNT_BYTES;
        for (int s = tid; s < BNT_BYTES / 16; s += 256)
            *(v4i*)(Bs + s * 16) = *(const v4i*)(src + s * 16);
    }
    __syncthreads();

    const int h = nt * 32 + (lane & 31);

    for (int mi = 0; mi < 4; ++mi) {
        const int mt = blockIdx.x * 16 + mi * 4 + wave;
        const uint8_t* ap = Ap + (size_t)mt * NK0 * 1024 + lane * 16;

        v16i acc[NSLICE] = {};
        v4i a_c = *(const v4i*)(ap);

        for (int k0 = 0; k0 < NK0; ++k0) {
            v4i a_n = (k0 < NK0 - 1) ? *(const v4i*)(ap + (size_t)(k0 + 1) * 1024) : a_c;
            #pragma unroll
            for (int j = 0; j < NSLICE; ++j) {
                v4i b = *(const v4i*)(Bs + (size_t)(k0 * NSLICE + j) * 1024 + lane * 16);
                acc[j] = __builtin_amdgcn_mfma_i32_32x32x32_i8(a_c, b, acc[j], 0, 0, 0);
            }
            a_c = a_n;
        }

        // recombine digits (exact integer Horner in fp64) and store
        #pragma unroll
        for (int r = 0; r < 16; ++r) {
            int mloc = (r & 3) + 8 * (r >> 2) + 4 * ghalf;
            double s = (double)acc[4][r];
            s = s * 256.0 + (double)acc[3][r];
            s = s * 256.0 + (double)acc[2][r];
            s = s * 256.0 + (double)acc[1][r];
            s = s * 256.0 + (double)acc[0][r];
            cur[(size_t)(mt * 32 + mloc) * H_SZ + h] = s * 0x1p-40;
        }
    }
}

// ---------------------------------------------------------------------------
// Phase 2: 50 LIF steps fp64, block = batch (256 thr). R7-verified (absmax 0,
// ~98 us, balanced VALU/L2). Unchanged.
// ---------------------------------------------------------------------------
__device__ __forceinline__ int build_list_pad(const unsigned long long* zm, int h,
                                              int* list) {
    unsigned long long w0 = zm[0], w1 = zm[1], w2 = zm[2], w3 = zm[3];
    int c0 = __popcll(w0), c1 = __popcll(w1), c2 = __popcll(w2), c3 = __popcll(w3);
    int wi = h >> 6;
    unsigned long long word = zm[wi];
    int base = (wi > 0 ? c0 : 0) + (wi > 1 ? c1 : 0) + (wi > 2 ? c2 : 0);
    int bit = h & 63;
    bool act = (word >> bit) & 1ull;
    int pos = __popcll(word & ((1ull << bit) - 1ull));
    if (act) list[base + pos] = h;
    int tot = c0 + c1 + c2 + c3;
    if (h < 8) list[tot + h] = 256;          // pad with zero-row index
    return tot;
}

__global__ __launch_bounds__(256) void snn_scan(const double* __restrict__ cur,
                                                const float* __restrict__ WrTz,
                                                const float* __restrict__ Wout,
                                                const float* __restrict__ bout,
                                                float* __restrict__ out) {
    const int b = blockIdx.x;
    const int h = threadIdx.x;

    __shared__ unsigned long long zmS[4];
    __shared__ int listS[2][H_SZ + 8];
    __shared__ float cntS[H_SZ];

    double v = 0.0, syn = 0.0;
    int cnt = 0;
    int nn[2] = {0, 0};

    const double* curb = cur + (size_t)b * H_SZ + h;
    const float*  wrh  = WrTz + h;
    double inp_c = curb[0];                   // prefetch t=0

    for (int t = 0; t < T_STEPS; ++t) {
        const int p = t & 1;
        int tn = (t < T_STEPS - 1) ? t + 1 : t;
        double inp_n = curb[(size_t)tn * B_SZ * H_SZ];

        double v_dec = v + 0.05 * ((0.0 - v) + syn);
        double i_dec = 0.9 * syn;
        bool   z_new = v_dec > 0.5;
        v = z_new ? 0.0 : v_dec;
        cnt += z_new ? 1 : 0;

        double r0 = 0.0, r1 = 0.0, r2 = 0.0, r3 = 0.0;
        const int* lp = listS[p];
        const int  n  = nn[p];
        for (int j = 0; j < n; j += 8) {
            float f0 = wrh[(size_t)lp[j + 0] * H_SZ];
            float f1 = wrh[(size_t)lp[j + 1] * H_SZ];
            float f2 = wrh[(size_t)lp[j + 2] * H_SZ];
            float f3 = wrh[(size_t)lp[j + 3] * H_SZ];
            float f4 = wrh[(size_t)lp[j + 4] * H_SZ];
            float f5 = wrh[(size_t)lp[j + 5] * H_SZ];
            float f6 = wrh[(size_t)lp[j + 6] * H_SZ];
            float f7 = wrh[(size_t)lp[j + 7] * H_SZ];
            r0 += (double)f0 + (double)f1;
            r1 += (double)f2 + (double)f3;
            r2 += (double)f4 + (double)f5;
            r3 += (double)f6 + (double)f7;
        }

        unsigned long long bal = __ballot((int)z_new);
        if ((h & 63) == 0) zmS[h >> 6] = bal;
        __syncthreads();
        nn[p ^ 1] = build_list_pad(zmS, h, listS[p ^ 1]);
        syn = (i_dec + inp_c) + ((r0 + r1) + (r2 + r3));
        inp_c = inp_n;
        __syncthreads();
    }

    cntS[h] = (float)cnt;
    __syncthreads();
    if (h < L_SZ) {
        double s = 0.0;
        for (int k = 0; k < H_SZ; ++k)
            s += (double)cntS[k] * (double)Wout[(size_t)h * H_SZ + k];
        s += (double)T_STEPS * (double)bout[h];
        out[(size_t)b * L_SZ + h] = (float)(s / (double)T_STEPS);
    }
}

// ---------------------------------------------------------------------------
extern "C" void kernel_launch(void* const* d_in, const int* in_sizes, int n_in,
                              void* d_out, int out_size, void* d_ws, size_t ws_size,
                              hipStream_t stream) {
    const float* x    = (const float*)d_in[0];   // [50,1024,784]
    const float* Wi   = (const float*)d_in[1];   // [256,784]
    const float* Wr   = (const float*)d_in[2];   // [256,256]
    const float* Wout = (const float*)d_in[3];   // [10,256]
    const float* bout = (const float*)d_in[4];   // [10]
    float* out = (float*)d_out;                  // [1024,10]

    // ws layout (~148.8 MB)
    char* ws = (char*)d_ws;
    double*  cur  = (double*)(ws);                       // 104,857,600 B
    float*   WrTz = (float*)(ws + 104857600);            // 257 x 256 x 4 = 263,168 B
    uint8_t* SBp  = (uint8_t*)(ws + 105121792);          //   1,064,960 B
    uint8_t* Ap   = (uint8_t*)(ws + 106186752);          //  42,598,400 B

    hipMemsetAsync(WrTz + 256 * H_SZ, 0, H_SZ * sizeof(float), stream);  // zero row
    hipLaunchKernelGGL(transpose_wr, dim3(8, 8), dim3(256), 0, stream, Wr, WrTz);
    hipLaunchKernelGGL(prep_packed, dim3(8, 13), dim3(128), 0, stream, Wi, SBp);
    hipLaunchKernelGGL(pack_x, dim3(M_TOT / 32), dim3(256), 0, stream, x, Ap);
    hipLaunchKernelGGL(gemm_i8L, dim3(100, 8), dim3(256), BNT_BYTES, stream,
                       Ap, SBp, cur);
    hipLaunchKernelGGL(snn_scan, dim3(B_SZ), dim3(256), 0, stream,
                       cur, WrTz, Wout, bout, out);
}

// Round 10
// 404.314 us; speedup vs baseline: 1.5125x; 1.5125x over previous
//
#include <hip/hip_runtime.h>
#include <cstdint>
#include <cstddef>

#define T_STEPS 50
#define B_SZ    1024
#define N_INP   784
#define H_SZ    256
#define L_SZ    10
#define M_TOT   (T_STEPS * B_SZ)   // 51200
#define NK0     26                 // K padded to 26*32 = 832
#define NSLICE  5                  // 5 balanced base-256 digits of rint(Wi*2^40): exact (|Wi|<0.5)
#define BNT_BYTES (NK0 * NSLICE * 1024)   // 133,120 B = one nt's B slices
#define CHB     20480              // chunk = 4 k0 = 20,480 B

typedef int v4i  __attribute__((ext_vector_type(4)));
typedef int v16i __attribute__((ext_vector_type(16)));

// ---------------------------------------------------------------------------
// Phase 0a: transpose Wr[h][k] (256x256, fp32) -> WrTz[k][h] (row 256 zeroed
// host-side memsetAsync; dummy gather offset hits it).  [R7-verified]
// ---------------------------------------------------------------------------
__global__ __launch_bounds__(256) void transpose_wr(const float* __restrict__ Wr,
                                                    float* __restrict__ WrTz) {
    __shared__ float tile[32][33];
    int bx = blockIdx.x * 32, by = blockIdx.y * 32;
    int tx = threadIdx.x % 32, ty = threadIdx.x / 32;   // 32 x 8
    #pragma unroll
    for (int j = 0; j < 32; j += 8)
        tile[ty + j][tx] = Wr[(size_t)(by + ty + j) * H_SZ + bx + tx];
    __syncthreads();
    #pragma unroll
    for (int j = 0; j < 32; j += 8)
        WrTz[(size_t)(bx + ty + j) * H_SZ + by + tx] = tile[tx][ty + j];
}

// ---------------------------------------------------------------------------
// Phase 0b: Wi -> 5 balanced int8 digits of rint(Wi*2^40), fragment-linear:
// SBp[((nt*26+k0)*5+j)*1024 + lane*16 + byte]; h = nt*32+(lane&31),
// k = k0*32+(lane>>5)*16+byte.  [R5-R9-verified exact, absmax 0]
// ---------------------------------------------------------------------------
__global__ __launch_bounds__(128) void prep_packed(const float* __restrict__ Wi,
                                                   uint8_t* __restrict__ SBp) {
    const int nt   = blockIdx.x;
    const int k0   = blockIdx.y * 2 + (threadIdx.x >> 6);
    const int lane = threadIdx.x & 63;
    const int h    = nt * 32 + (lane & 31);
    const int g    = k0 * 2 + (lane >> 5);     // 16-float group index

    int wd[NSLICE][4] = {};
    #pragma unroll
    for (int u = 0; u < 16; ++u) {
        double wv = 0.0;
        if (g < 49) wv = (double)Wi[(size_t)h * N_INP + g * 16 + u];
        double r = rint(wv * 0x1p40);
        #pragma unroll
        for (int j = 0; j < NSLICE - 1; ++j) {
            double q  = floor((r + 128.0) * 0.00390625);
            double dj = r - 256.0 * q;                     // in [-128,127]
            wd[j][u >> 2] |= ((int)dj & 0xFF) << ((u & 3) * 8);
            r = q;
        }
        wd[NSLICE - 1][u >> 2] |= ((int)r & 0xFF) << ((u & 3) * 8);
    }
    uint8_t* base = SBp + ((size_t)(nt * NK0 + k0) * NSLICE) * 1024 + lane * 16;
    #pragma unroll
    for (int j = 0; j < NSLICE; ++j)
        *(v4i*)(base + (size_t)j * 1024) = (v4i){wd[j][0], wd[j][1], wd[j][2], wd[j][3]};
}

// ---------------------------------------------------------------------------
// Phase 0c: pack X (binary fp32) -> fragment-linear int8 (R6-R9-verified).
// Ap[(mt*26+k0)*1024 + lane*16 + byte]
// ---------------------------------------------------------------------------
__global__ __launch_bounds__(256) void pack_x(const float* __restrict__ X,
                                              uint8_t* __restrict__ Ap) {
    const int mt  = blockIdx.x;       // 1600
    const int tid = threadIdx.x;
    #pragma unroll
    for (int i = 0; i < 7; ++i) {
        int s = tid + i * 256;
        if (s < NK0 * 64) {
            int k0 = s >> 6, lane = s & 63;
            int m = mt * 32 + (lane & 31);
            int g = k0 * 2 + (lane >> 5);
            unsigned int bw[4] = {0u, 0u, 0u, 0u};
            if (g < 49) {
                const float* src = X + (size_t)m * N_INP + g * 16;
                #pragma unroll
                for (int q = 0; q < 4; ++q) {
                    float4 f = *(const float4*)(src + q * 4);
                    bw[q] = (f.x != 0.f ? 1u : 0u) | (f.y != 0.f ? 0x100u : 0u)
                          | (f.z != 0.f ? 0x10000u : 0u) | (f.w != 0.f ? 0x1000000u : 0u);
                }
            }
            *(v4i*)(Ap + ((size_t)(mt * NK0 + k0)) * 1024 + lane * 16) =
                (v4i){(int)bw[0], (int)bw[1], (int)bw[2], (int)bw[3]};
        }
    }
}

// ---------------------------------------------------------------------------
// Phase 1: cur = X @ Wi.T exactly via 5 int8-digit MFMAs.  R7 structure
// (proven best) with 4-k0 chunks: block = 4 waves, each wave owns TWO
// m-tiles (ds_read feeds 2 MFMAs), double-buffered 2x20 KB LDS staging of
// B, 7 barriers/nt (was 13). A fragments reloaded after use (shallow
// prefetch) keeps VGPR ~215; __launch_bounds__(256,2) pins the 256-reg
// budget so the R8/R9 spill mode can't recur. Grid (200, 8).
// ---------------------------------------------------------------------------
__global__ __launch_bounds__(256, 2) void gemm_i8c(const uint8_t* __restrict__ Ap,
                                                   const uint8_t* __restrict__ SBp,
                                                   double* __restrict__ cur) {
    __shared__ __align__(16) uint8_t Bs[2][CHB];   // 2 x 20 KB

    const int tid   = threadIdx.x;
    const int wave  = tid >> 6;
    const int lane  = tid & 63;
    const int ghalf = lane >> 5;
    const int nt    = blockIdx.y;
    const int mt0   = (blockIdx.x * 4 + wave) * 2;   // wave owns mt0, mt0+1
    const int mt1   = mt0 + 1;

    const uint8_t* ap0 = Ap + (size_t)mt0 * NK0 * 1024 + lane * 16;
    const uint8_t* ap1 = Ap + (size_t)mt1 * NK0 * 1024 + lane * 16;
    const uint8_t* bbase = SBp + (size_t)nt * BNT_BYTES;

    // stage chunk 0 (k0 = 0..3, 1280 slots) + load A chunk 0
    #pragma unroll
    for (int i = 0; i < 5; ++i) {
        int s = tid + i * 256;
        *(v4i*)(Bs[0] + s * 16) = *(const v4i*)(bbase + s * 16);
    }
    v4i a0[4], a1[4];
    #pragma unroll
    for (int i = 0; i < 4; ++i) {
        a0[i] = *(const v4i*)(ap0 + (size_t)i * 1024);
        a1[i] = *(const v4i*)(ap1 + (size_t)i * 1024);
    }
    __syncthreads();

    v16i acc0[NSLICE] = {};
    v16i acc1[NSLICE] = {};

    for (int c = 0; c < 7; ++c) {
        const int cb = c & 1;
        const int kc = (c < 6) ? 4 : 2;

        // stage next chunk into the other buffer (independent of MFMAs)
        if (c < 6) {
            const int slots_n = (c + 1 < 6) ? (CHB / 16) : (CHB / 32);
            const uint8_t* src = bbase + (size_t)(c + 1) * CHB;
            #pragma unroll
            for (int i = 0; i < 5; ++i) {
                int s = tid + i * 256;
                if (s < slots_n)
                    *(v4i*)(Bs[cb ^ 1] + s * 16) = *(const v4i*)(src + s * 16);
            }
        }

        // compute current chunk
        for (int dk = 0; dk < kc; ++dk) {
            v4i aa0 = a0[dk];
            v4i aa1 = a1[dk];
            #pragma unroll
            for (int j = 0; j < NSLICE; ++j) {
                v4i b = *(const v4i*)(Bs[cb] + (dk * NSLICE + j) * 1024 + lane * 16);
                acc0[j] = __builtin_amdgcn_mfma_i32_32x32x32_i8(aa0, b, acc0[j], 0, 0, 0);
                acc1[j] = __builtin_amdgcn_mfma_i32_32x32x32_i8(aa1, b, acc1[j], 0, 0, 0);
            }
        }

        // reload A for next chunk (after use; latency partially covered by barrier)
        if (c < 6) {
            const int kn = (c + 1 < 6) ? 4 : 2;
            for (int i = 0; i < kn; ++i) {
                a0[i] = *(const v4i*)(ap0 + (size_t)((c + 1) * 4 + i) * 1024);
                a1[i] = *(const v4i*)(ap1 + (size_t)((c + 1) * 4 + i) * 1024);
            }
        }
        __syncthreads();
    }

    // recombine digits (exact integer Horner in fp64) and store both m-tiles
    const int h = nt * 32 + (lane & 31);
    #pragma unroll
    for (int r = 0; r < 16; ++r) {
        int mloc = (r & 3) + 8 * (r >> 2) + 4 * ghalf;
        double s0 = (double)acc0[4][r];
        s0 = s0 * 256.0 + (double)acc0[3][r];
        s0 = s0 * 256.0 + (double)acc0[2][r];
        s0 = s0 * 256.0 + (double)acc0[1][r];
        s0 = s0 * 256.0 + (double)acc0[0][r];
        cur[(size_t)(mt0 * 32 + mloc) * H_SZ + h] = s0 * 0x1p-40;
        double s1 = (double)acc1[4][r];
        s1 = s1 * 256.0 + (double)acc1[3][r];
        s1 = s1 * 256.0 + (double)acc1[2][r];
        s1 = s1 * 256.0 + (double)acc1[1][r];
        s1 = s1 * 256.0 + (double)acc1[0][r];
        cur[(size_t)(mt1 * 32 + mloc) * H_SZ + h] = s1 * 0x1p-40;
    }
}

// ---------------------------------------------------------------------------
// Phase 2: 50 LIF steps fp64, block = batch (256 thr). R7 kernel with an
// addressing diet: spike list stores BYTE offsets (k<<10) so each gathered
// row is one v_add + load (no per-row 64-bit shift-add chain). Pad offset
// 256<<10 hits the zeroed row of WrTz.
// ---------------------------------------------------------------------------
__device__ __forceinline__ int build_list_pad(const unsigned long long* zm, int h,
                                              int* list) {
    unsigned long long w0 = zm[0], w1 = zm[1], w2 = zm[2], w3 = zm[3];
    int c0 = __popcll(w0), c1 = __popcll(w1), c2 = __popcll(w2), c3 = __popcll(w3);
    int wi = h >> 6;
    unsigned long long word = zm[wi];
    int base = (wi > 0 ? c0 : 0) + (wi > 1 ? c1 : 0) + (wi > 2 ? c2 : 0);
    int bit = h & 63;
    bool act = (word >> bit) & 1ull;
    int pos = __popcll(word & ((1ull << bit) - 1ull));
    if (act) list[base + pos] = h << 10;         // byte offset of row h
    int tot = c0 + c1 + c2 + c3;
    if (h < 8) list[tot + h] = 256 << 10;        // pad -> zero row
    return tot;
}

__global__ __launch_bounds__(256) void snn_scan(const double* __restrict__ cur,
                                                const float* __restrict__ WrTz,
                                                const float* __restrict__ Wout,
                                                const float* __restrict__ bout,
                                                float* __restrict__ out) {
    const int b = blockIdx.x;
    const int h = threadIdx.x;

    __shared__ unsigned long long zmS[4];
    __shared__ int listS[2][H_SZ + 8];
    __shared__ float cntS[H_SZ];

    double v = 0.0, syn = 0.0;
    int cnt = 0;
    int nn[2] = {0, 0};

    const double* curb = cur + (size_t)b * H_SZ + h;
    const char*   wrb  = (const char*)WrTz + h * 4;   // column base (bytes)
    double inp_c = curb[0];                           // prefetch t=0

    for (int t = 0; t < T_STEPS; ++t) {
        const int p = t & 1;
        int tn = (t < T_STEPS - 1) ? t + 1 : t;
        double inp_n = curb[(size_t)tn * B_SZ * H_SZ];

        double v_dec = v + 0.05 * ((0.0 - v) + syn);
        double i_dec = 0.9 * syn;
        bool   z_new = v_dec > 0.5;
        v = z_new ? 0.0 : v_dec;
        cnt += z_new ? 1 : 0;

        double r0 = 0.0, r1 = 0.0, r2 = 0.0, r3 = 0.0;
        const int* lp = listS[p];
        const int  n  = nn[p];
        for (int j = 0; j < n; j += 8) {
            float f0 = *(const float*)(wrb + lp[j + 0]);
            float f1 = *(const float*)(wrb + lp[j + 1]);
            float f2 = *(const float*)(wrb + lp[j + 2]);
            float f3 = *(const float*)(wrb + lp[j + 3]);
            float f4 = *(const float*)(wrb + lp[j + 4]);
            float f5 = *(const float*)(wrb + lp[j + 5]);
            float f6 = *(const float*)(wrb + lp[j + 6]);
            float f7 = *(const float*)(wrb + lp[j + 7]);
            r0 += (double)f0 + (double)f1;
            r1 += (double)f2 + (double)f3;
            r2 += (double)f4 + (double)f5;
            r3 += (double)f6 + (double)f7;
        }

        unsigned long long bal = __ballot((int)z_new);
        if ((h & 63) == 0) zmS[h >> 6] = bal;
        __syncthreads();
        nn[p ^ 1] = build_list_pad(zmS, h, listS[p ^ 1]);
        syn = (i_dec + inp_c) + ((r0 + r1) + (r2 + r3));
        inp_c = inp_n;
        __syncthreads();
    }

    cntS[h] = (float)cnt;
    __syncthreads();
    if (h < L_SZ) {
        double s = 0.0;
        for (int k = 0; k < H_SZ; ++k)
            s += (double)cntS[k] * (double)Wout[(size_t)h * H_SZ + k];
        s += (double)T_STEPS * (double)bout[h];
        out[(size_t)b * L_SZ + h] = (float)(s / (double)T_STEPS);
    }
}

// ---------------------------------------------------------------------------
extern "C" void kernel_launch(void* const* d_in, const int* in_sizes, int n_in,
                              void* d_out, int out_size, void* d_ws, size_t ws_size,
                              hipStream_t stream) {
    const float* x    = (const float*)d_in[0];   // [50,1024,784]
    const float* Wi   = (const float*)d_in[1];   // [256,784]
    const float* Wr   = (const float*)d_in[2];   // [256,256]
    const float* Wout = (const float*)d_in[3];   // [10,256]
    const float* bout = (const float*)d_in[4];   // [10]
    float* out = (float*)d_out;                  // [1024,10]

    // ws layout (~148.8 MB)
    char* ws = (char*)d_ws;
    double*  cur  = (double*)(ws);                       // 104,857,600 B
    float*   WrTz = (float*)(ws + 104857600);            // 257 x 256 x 4 = 263,168 B
    uint8_t* SBp  = (uint8_t*)(ws + 105121792);          //   1,064,960 B
    uint8_t* Ap   = (uint8_t*)(ws + 106186752);          //  42,598,400 B

    hipMemsetAsync(WrTz + 256 * H_SZ, 0, H_SZ * sizeof(float), stream);  // zero row
    hipLaunchKernelGGL(transpose_wr, dim3(8, 8), dim3(256), 0, stream, Wr, WrTz);
    hipLaunchKernelGGL(prep_packed, dim3(8, 13), dim3(128), 0, stream, Wi, SBp);
    hipLaunchKernelGGL(pack_x, dim3(M_TOT / 32), dim3(256), 0, stream, x, Ap);
    hipLaunchKernelGGL(gemm_i8c, dim3(200, 8), dim3(256), 0, stream, Ap, SBp, cur);
    hipLaunchKernelGGL(snn_scan, dim3(B_SZ), dim3(256), 0, stream,
                       cur, WrTz, Wout, bout, out);
}